// Round 7
// baseline (147.234 us; speedup 1.0000x reference)
//
#include <hip/hip_runtime.h>
#include <hip/hip_bf16.h>

typedef short bf16x8 __attribute__((ext_vector_type(8)));
typedef float f32x4 __attribute__((ext_vector_type(4)));

#define HID 128
#define NRAD 6
#define TILE 128   // 128 edges per block: 16 per wave-slot x 2 halves

static __device__ __forceinline__ unsigned short f2bf(float f) {
    union { float f; unsigned u; } v; v.f = f;
    unsigned r = v.u + 0x7FFFu + ((v.u >> 16) & 1u);
    return (unsigned short)(r >> 16);
}

static __device__ __forceinline__ float swishf(float z) {
    return z * __builtin_amdgcn_rcpf(1.0f + __expf(-z));
}

// ---------------------------------------------------------------------------
// Precompute: P1[v] = emb[v]@W1 + b_lin, P2[v] = emb[v]@W2, Wt = (W3^T) bf16
// ---------------------------------------------------------------------------
__global__ void precompute_kernel(const float* __restrict__ emb,
                                  const float* __restrict__ w_lin,
                                  const float* __restrict__ b_lin,
                                  float* __restrict__ P1,
                                  float* __restrict__ P2,
                                  unsigned short* __restrict__ Wt) {
    const int b = blockIdx.x;
    const int t = threadIdx.x; // 0..127 = output column n
    if (b < 190) {
        const int v = (b < 95) ? b : b - 95;
        const float* W = w_lin + (b < 95 ? 0 : HID * HID);
        float acc = (b < 95) ? b_lin[t] : 0.0f;
        #pragma unroll 4
        for (int k = 0; k < HID; ++k)
            acc = fmaf(emb[v * HID + k], W[k * HID + t], acc);
        (b < 95 ? P1 : P2)[v * HID + t] = acc;
    } else {
        const int kr = b - 190; // 0..127
        Wt[t * HID + kr] = f2bf(w_lin[(2 * HID + kr) * HID + t]);
    }
}

// ---------------------------------------------------------------------------
// Persistent edge kernel — LDS READ-ONLY after one staging barrier.
// Each lane handles TWO edges (e0 = base+elane, e1 = e0+64): every sB/s_w
// LDS read feeds two compute streams (2x arithmetic per LDS byte, 2x ILP).
// Software-pipelined rbf/ei/ej loads one tile ahead; x[] gather resolved at
// loop top, consumed in the epilogue.
// ---------------------------------------------------------------------------
__global__ __launch_bounds__(256, 1) void edge_kernel(
    const float* __restrict__ rbf, const int* __restrict__ ei,
    const int* __restrict__ ej, const int* __restrict__ x,
    const float* __restrict__ w_rbf, const float* __restrict__ b_rbf,
    const float* __restrict__ P1, const float* __restrict__ P2,
    const unsigned short* __restrict__ Wt,
    float* __restrict__ out, int E, int ntiles)
{
    __shared__ __align__(16) float s_w[7 * HID];             // w_rbf rows 0..5, b_rbf row 6
    __shared__ __align__(16) unsigned short sB[HID * HID];   // W3^T bf16, XOR-swizzled

    const int t = threadIdx.x;
    const int w = t >> 6, l = t & 63, lr = l & 15, lg = l >> 4;

    // ---- one-time read-only staging ----
    for (int idx = t; idx < NRAD * HID; idx += 256) s_w[idx] = w_rbf[idx];
    if (t < HID) s_w[6 * HID + t] = b_rbf[t];
    {
        const uint4* g = (const uint4*)Wt;
        #pragma unroll
        for (int q = 0; q < 8; ++q) {
            int gi = q * 256 + t;                 // coalesced
            int n = gi >> 4, cc = gi & 15;
            uint4 v = g[gi];
            *(uint4*)((char*)sB + n * 256 + ((cc * 16) ^ ((n & 7) << 4))) = v;
        }
    }
    __syncthreads();   // the ONLY barrier; LDS never written again

    const int n0base = lg * 8;
    const int elane = w * 16 + lr;               // lane's edge offset within tile

    int tile = blockIdx.x;

    // ---- pipeline preload: tile 0 inputs (both halves) ----
    float2 a01, a23, a45, b01, b23, b45;
    int iia, jja, iib, jjb;
    {
        const int e0 = min(tile * TILE + elane, E - 1);
        const int e1 = min(tile * TILE + 64 + elane, E - 1);
        const float* rpa = rbf + (size_t)e0 * NRAD;
        const float* rpb = rbf + (size_t)e1 * NRAD;
        a01 = *(const float2*)(rpa); a23 = *(const float2*)(rpa + 2); a45 = *(const float2*)(rpa + 4);
        b01 = *(const float2*)(rpb); b23 = *(const float2*)(rpb + 2); b45 = *(const float2*)(rpb + 4);
        iia = ei[e0]; jja = ej[e0];
        iib = ei[e1]; jjb = ej[e1];
    }

    for (; tile < ntiles; tile += gridDim.x) {
        const int e0 = tile * TILE + elane;
        const int e1 = e0 + 64;

        // resolve current tile's x-gathers now (consumed ~1500cy later)
        const int xia = x[iia], xja = x[jja];
        const int xib = x[iib], xjb = x[jjb];
        const float ra0 = a01.x, ra1 = a01.y, ra2 = a23.x,
                    ra3 = a23.y, ra4 = a45.x, ra5 = a45.y;
        const float rb0 = b01.x, rb1 = b01.y, rb2 = b23.x,
                    rb3 = b23.y, rb4 = b45.x, rb5 = b45.y;

        // issue NEXT tile's streaming loads (hide under this tile's compute)
        float2 na01, na23, na45, nb01, nb23, nb45;
        int nia, nja, nib, njb;
        {
            const int tn = tile + gridDim.x;
            const int bn = (tn < ntiles ? tn : tile) * TILE;
            const int en0 = min(bn + elane, E - 1);
            const int en1 = min(bn + 64 + elane, E - 1);
            const float* rpa = rbf + (size_t)en0 * NRAD;
            const float* rpb = rbf + (size_t)en1 * NRAD;
            na01 = *(const float2*)(rpa); na23 = *(const float2*)(rpa + 2); na45 = *(const float2*)(rpa + 4);
            nb01 = *(const float2*)(rpb); nb23 = *(const float2*)(rpb + 2); nb45 = *(const float2*)(rpb + 4);
            nia = ei[en0]; nja = ej[en0];
            nib = ei[en1]; njb = ej[en1];
        }

        // ---- build B-fragments for BOTH edges (shared s_w reads) ----
        bf16x8 afa[4], afb[4];
        #pragma unroll
        for (int kk = 0; kk < 4; ++kk) {
            const int n0 = kk * 32 + n0base;
            const f32x4 bz0 = *(const f32x4*)(s_w + 6 * HID + n0);
            const f32x4 bz1 = *(const f32x4*)(s_w + 6 * HID + n0 + 4);
            f32x4 za0 = bz0, za1 = bz1, zb0 = bz0, zb1 = bz1;
            #define RSTEP(q, rqa, rqb)                                     \
            {                                                              \
                const f32x4 w0 = *(const f32x4*)(s_w + (q) * HID + n0);    \
                const f32x4 w1 = *(const f32x4*)(s_w + (q) * HID + n0 + 4);\
                _Pragma("unroll")                                          \
                for (int u = 0; u < 4; ++u) {                              \
                    za0[u] = fmaf(rqa, w0[u], za0[u]);                     \
                    za1[u] = fmaf(rqa, w1[u], za1[u]);                     \
                    zb0[u] = fmaf(rqb, w0[u], zb0[u]);                     \
                    zb1[u] = fmaf(rqb, w1[u], zb1[u]);                     \
                }                                                          \
            }
            RSTEP(0, ra0, rb0) RSTEP(1, ra1, rb1) RSTEP(2, ra2, rb2)
            RSTEP(3, ra3, rb3) RSTEP(4, ra4, rb4) RSTEP(5, ra5, rb5)
            #undef RSTEP
            union { unsigned short s[8]; bf16x8 v; } pa, pb;
            #pragma unroll
            for (int u = 0; u < 4; ++u) {
                pa.s[u]     = f2bf(swishf(za0[u]));
                pa.s[4 + u] = f2bf(swishf(za1[u]));
                pb.s[u]     = f2bf(swishf(zb0[u]));
                pb.s[4 + u] = f2bf(swishf(zb1[u]));
            }
            afa[kk] = pa.v;
            afb[kk] = pb.v;
        }

        // ---- per-fragment MFMA (shared bb reads) + immediate epilogue ----
        const bool va = (e0 < E), vb = (e1 < E);
        const float* p1a = P1 + xia * HID;
        const float* p2a = P2 + xja * HID;
        const float* p1b = P1 + xib * HID;
        const float* p2b = P2 + xjb * HID;
        float* opa = out + (size_t)e0 * HID;
        float* opb = out + (size_t)e1 * HID;

        #pragma unroll
        for (int f = 0; f < 8; ++f) {
            f32x4 acca = (f32x4){0.f, 0.f, 0.f, 0.f};
            f32x4 accb = (f32x4){0.f, 0.f, 0.f, 0.f};
            const int rowB = f * 16 + lr;
            const int rB = rowB * 256, sw = (rowB & 7) << 4;
            #pragma unroll
            for (int kk = 0; kk < 4; ++kk) {
                const int colb = kk * 64 + lg * 16;
                bf16x8 bb = *(const bf16x8*)((const char*)sB + rB + (colb ^ sw));
                acca = __builtin_amdgcn_mfma_f32_16x16x32_bf16(bb, afa[kk], acca, 0, 0, 0);
                accb = __builtin_amdgcn_mfma_f32_16x16x32_bf16(bb, afb[kk], accb, 0, 0, 0);
            }
            const int n0 = f * 16 + lg * 4;
            if (va) {
                const f32x4 x1 = *(const f32x4*)(p1a + n0);
                const f32x4 x2 = *(const f32x4*)(p2a + n0);
                f32x4 v;
                #pragma unroll
                for (int u = 0; u < 4; ++u)
                    v[u] = swishf(acca[u] + x1[u] + x2[u]);
                *(f32x4*)(opa + n0) = v;
            }
            if (vb) {
                const f32x4 x1 = *(const f32x4*)(p1b + n0);
                const f32x4 x2 = *(const f32x4*)(p2b + n0);
                f32x4 v;
                #pragma unroll
                for (int u = 0; u < 4; ++u)
                    v[u] = swishf(accb[u] + x1[u] + x2[u]);
                *(f32x4*)(opb + n0) = v;
            }
        }

        // rotate pipeline registers
        a01 = na01; a23 = na23; a45 = na45;
        b01 = nb01; b23 = nb23; b45 = nb45;
        iia = nia; jja = nja; iib = nib; jjb = njb;
    }
}

extern "C" void kernel_launch(void* const* d_in, const int* in_sizes, int n_in,
                              void* d_out, int out_size, void* d_ws, size_t ws_size,
                              hipStream_t stream) {
    const int*   x     = (const int*)  d_in[0];
    const float* rbf   = (const float*)d_in[1];
    const int*   ei    = (const int*)  d_in[2];
    const int*   ej    = (const int*)  d_in[3];
    const float* emb   = (const float*)d_in[4];
    const float* w_rbf = (const float*)d_in[5];
    const float* b_rbf = (const float*)d_in[6];
    const float* w_lin = (const float*)d_in[7];
    const float* b_lin = (const float*)d_in[8];
    float* out = (float*)d_out;
    const int E = in_sizes[2];

    // workspace: P1 (95*128 f32), P2, Wt (128x128 bf16)
    float* P1 = (float*)d_ws;
    float* P2 = (float*)((char*)d_ws + 49152);
    unsigned short* Wt = (unsigned short*)((char*)d_ws + 98304);

    hipLaunchKernelGGL(precompute_kernel, dim3(318), dim3(128), 0, stream,
                       emb, w_lin, b_lin, P1, P2, Wt);

    const int ntiles = (E + TILE - 1) / TILE;
    const int nblk = ntiles < 1024 ? ntiles : 1024;
    hipLaunchKernelGGL(edge_kernel, dim3(nblk), dim3(256), 0, stream,
                       rbf, ei, ej, x, w_rbf, b_rbf, P1, P2, Wt, out, E, ntiles);
}